// Round 1
// baseline (475.598 us; speedup 1.0000x reference)
//
#include <hip/hip_runtime.h>
#include <hip/hip_fp16.h>
#include <cstdint>
#include <cstddef>

typedef _Float16 f16x8 __attribute__((ext_vector_type(8)));
typedef _Float16 f16x4 __attribute__((ext_vector_type(4)));
typedef float    f32x4 __attribute__((ext_vector_type(4)));

// ---------------------------------------------------------------------------
// fake-quant with fractional bit-width interpolation (matches jax reference)
//   a = max(alpha, 1); blo = floor(a); frac = a - blo
//   s_lo = 2^blo - 1 ; s_hi = 2^(blo+1) - 1 = 2*s_lo + 1 (exact)
//   q = (1-frac)*round(clip*s_lo)/s_lo + frac*round(clip*s_hi)/s_hi
// rintf == round-half-to-even == jnp.round
// ---------------------------------------------------------------------------
__device__ __forceinline__ float quant_interp(float v, float alpha) {
    float a    = fmaxf(alpha, 1.0f);
    float blo  = floorf(a);
    float frac = a - blo;
    float slo  = exp2f(blo) - 1.0f;
    float shi  = 2.0f * slo + 1.0f;
    float c    = fminf(fmaxf(v, -1.0f), 1.0f);
    float qlo  = rintf(c * slo) / slo;
    float qhi  = rintf(c * shi) / shi;
    return (1.0f - frac) * qlo + frac * qhi;
}

// ---------------------------------------------------------------------------
// column mean of alpha_a [OUT][IN] -> a_feat [IN], deterministic two-pass
// ---------------------------------------------------------------------------
__global__ void colsum_partial_kernel(const float* __restrict__ aA,
                                      float* __restrict__ partial,
                                      int IN, int rows_per) {
    int col = blockIdx.x * blockDim.x + threadIdx.x;
    size_t r0 = (size_t)blockIdx.y * rows_per;
    float s = 0.f;
    for (int r = 0; r < rows_per; ++r)
        s += aA[(r0 + r) * (size_t)IN + col];
    partial[(size_t)blockIdx.y * IN + col] = s;
}

__global__ void colsum_final_kernel(const float* __restrict__ partial,
                                    float* __restrict__ afeat,
                                    int IN, int nchunk, float inv) {
    int col = blockIdx.x * blockDim.x + threadIdx.x;
    float s = 0.f;
    for (int c = 0; c < nchunk; ++c)
        s += partial[(size_t)c * IN + col];
    afeat[col] = s * inv;
}

// ---------------------------------------------------------------------------
// quantize x [M][IN] with per-column alpha -> fp16
// ---------------------------------------------------------------------------
__global__ void quant_x_kernel(const float* __restrict__ x,
                               const float* __restrict__ afeat,
                               f16x4* __restrict__ qx, int IN, size_t n4) {
    size_t i = (size_t)blockIdx.x * blockDim.x + threadIdx.x;
    size_t stride = (size_t)gridDim.x * blockDim.x;
    for (; i < n4; i += stride) {
        size_t e = i * 4;
        int col = (int)(e % (size_t)IN);            // multiple of 4
        f32x4 xv = *(const f32x4*)(x + e);
        f32x4 av = *(const f32x4*)(afeat + col);
        f16x4 o;
        #pragma unroll
        for (int j = 0; j < 4; ++j) o[j] = (_Float16)quant_interp(xv[j], av[j]);
        qx[i] = o;
    }
}

// quantize w [OUT][IN] with per-element alpha -> fp16
__global__ void quant_w_kernel(const float* __restrict__ w,
                               const float* __restrict__ aw,
                               f16x4* __restrict__ qw, size_t n4) {
    size_t i = (size_t)blockIdx.x * blockDim.x + threadIdx.x;
    size_t stride = (size_t)gridDim.x * blockDim.x;
    for (; i < n4; i += stride) {
        f32x4 wv = *(const f32x4*)(w + i * 4);
        f32x4 av = *(const f32x4*)(aw + i * 4);
        f16x4 o;
        #pragma unroll
        for (int j = 0; j < 4; ++j) o[j] = (_Float16)quant_interp(wv[j], av[j]);
        qw[i] = o;
    }
}

// ---------------------------------------------------------------------------
// NT GEMM: C[M][N] = A[M][K] * B[N][K]^T + bias[N], fp16 in, fp32 out
// 128x128 tile, BK=64, 4 waves (2x2), wave tile 64x64 = 4x4 frags of 16x16
// global_load_lds width-16 staging; XOR swizzle (slot ^= row&7) applied to the
// GLOBAL source (linear LDS dest) and to the LDS read -- rule #21.
// ---------------------------------------------------------------------------
__device__ __forceinline__ void gload_lds16(const void* g, void* l) {
    __builtin_amdgcn_global_load_lds(
        (const __attribute__((address_space(1))) void*)g,
        (__attribute__((address_space(3))) void*)l,
        16, 0, 0);
}

__global__ __launch_bounds__(256) void gemm_qf16_kernel(
    const _Float16* __restrict__ A,   // [M][K] qx
    const _Float16* __restrict__ B,   // [N][K] qw
    const float* __restrict__ bias,   // [N]
    float* __restrict__ C,            // [M][N]
    int M, int N, int K)
{
    constexpr int BM = 128, BN = 128, BK = 64;
    __shared__ _Float16 As[BM * BK];   // 16 KiB, row-major, 128B rows (8 slots of 16B)
    __shared__ _Float16 Bs[BN * BK];   // 16 KiB

    const int tid  = threadIdx.x;
    const int lane = tid & 63;
    const int wave = tid >> 6;
    const int wm   = (wave >> 1) * 64;
    const int wn   = (wave & 1) * 64;
    const int r15  = lane & 15;
    const int hi   = lane >> 4;

    const int nbx = N / BN;
    const int nwg = (M / BM) * nbx;
    const int bid = (int)blockIdx.x;
    // XCD-aware swizzle (bijective since nwg % 8 == 0; fall back otherwise)
    const int swz = (nwg & 7) ? bid : ((bid & 7) * (nwg >> 3) + (bid >> 3));
    const size_t bm0 = (size_t)(swz / nbx) * BM;
    const size_t bn0 = (size_t)(swz % nbx) * BN;

    const int tbase0 = wave * 64 + lane;   // staging task base

    f32x4 acc[4][4] = {};

    const int nkt = K / BK;
    for (int kt = 0; kt < nkt; ++kt) {
        const _Float16* Ag = A + bm0 * K + (size_t)kt * BK;
        const _Float16* Bg = B + bn0 * K + (size_t)kt * BK;
        // stage 128 rows x 64 halfs for A and B: 1024 16B tasks each,
        // 4 instructions per wave per matrix; LDS dest linear, source swizzled
        #pragma unroll
        for (int i = 0; i < 4; ++i) {
            int t    = i * 256 + tbase0;
            int row  = t >> 3;
            int sg   = (t & 7) ^ (row & 7);         // inverse-swizzled global slot
            int ldsb = (i * 256 + wave * 64) * 16;  // wave-uniform LDS byte base
            gload_lds16(Ag + (size_t)row * K + sg * 8, (char*)As + ldsb);
            gload_lds16(Bg + (size_t)row * K + sg * 8, (char*)Bs + ldsb);
        }
        __syncthreads();   // compiler drains vmcnt(0) before s_barrier

        f16x8 af[4][2], bf[4][2];
        #pragma unroll
        for (int m = 0; m < 4; ++m) {
            int row = wm + m * 16 + r15;
            #pragma unroll
            for (int ks = 0; ks < 2; ++ks) {
                int slot = ks * 4 + hi;
                af[m][ks] = *(const f16x8*)((const char*)As + row * 128 +
                                            ((slot ^ (row & 7)) << 4));
            }
        }
        #pragma unroll
        for (int n = 0; n < 4; ++n) {
            int row = wn + n * 16 + r15;
            #pragma unroll
            for (int ks = 0; ks < 2; ++ks) {
                int slot = ks * 4 + hi;
                bf[n][ks] = *(const f16x8*)((const char*)Bs + row * 128 +
                                            ((slot ^ (row & 7)) << 4));
            }
        }

        #pragma unroll
        for (int m = 0; m < 4; ++m)
            #pragma unroll
            for (int n = 0; n < 4; ++n) {
                acc[m][n] = __builtin_amdgcn_mfma_f32_16x16x32_f16(
                                af[m][0], bf[n][0], acc[m][n], 0, 0, 0);
                acc[m][n] = __builtin_amdgcn_mfma_f32_16x16x32_f16(
                                af[m][1], bf[n][1], acc[m][n], 0, 0, 0);
            }
        __syncthreads();
    }

    // epilogue: C/D layout col = lane&15, row = (lane>>4)*4 + reg
    #pragma unroll
    for (int n = 0; n < 4; ++n) {
        size_t col = bn0 + wn + n * 16 + r15;
        float bv = bias[col];
        #pragma unroll
        for (int m = 0; m < 4; ++m) {
            size_t rbase = bm0 + wm + m * 16 + hi * 4;
            #pragma unroll
            for (int r = 0; r < 4; ++r)
                C[(rbase + r) * N + col] = acc[m][n][r] + bv;
        }
    }
}

// ---------------------------------------------------------------------------
extern "C" void kernel_launch(void* const* d_in, const int* in_sizes, int n_in,
                              void* d_out, int out_size, void* d_ws, size_t ws_size,
                              hipStream_t stream) {
    const float* x    = (const float*)d_in[0];
    const float* w    = (const float*)d_in[1];
    const float* bias = (const float*)d_in[2];
    const float* aw   = (const float*)d_in[3];
    const float* aA   = (const float*)d_in[4];

    const int    OUT = in_sizes[2];
    const size_t wsz = (size_t)in_sizes[1];
    const int    IN  = (int)(wsz / OUT);
    const int    M   = in_sizes[0] / IN;    // 8192
    const int    N   = OUT;                 // 4096
    const int    K   = IN;                  // 4096

    char* ws = (char*)d_ws;
    _Float16* qx = (_Float16*)ws;                                   // M*K*2
    _Float16* qw = (_Float16*)(ws + (size_t)M * K * 2);             // N*K*2
    float* afeat   = (float*)(ws + (size_t)M * K * 2 + (size_t)N * K * 2);
    float* partial = afeat + K;                                     // 32*K

    const int NCHUNK = 32;
    dim3 g1(K / 256, NCHUNK);
    colsum_partial_kernel<<<g1, 256, 0, stream>>>(aA, partial, K, OUT / NCHUNK);
    colsum_final_kernel<<<K / 256, 256, 0, stream>>>(partial, afeat, K, NCHUNK,
                                                     1.0f / (float)OUT);

    quant_x_kernel<<<2048, 256, 0, stream>>>(x, afeat, (f16x4*)qx, K,
                                             (size_t)M * K / 4);
    quant_w_kernel<<<2048, 256, 0, stream>>>(w, aw, (f16x4*)qw,
                                             (size_t)N * K / 4);

    const int nwg = (M / 128) * (N / 128);
    gemm_qf16_kernel<<<nwg, 256, 0, stream>>>(qx, qw, bias, (float*)d_out,
                                              M, N, K);
}

// Round 2
// 455.047 us; speedup vs baseline: 1.0452x; 1.0452x over previous
//
#include <hip/hip_runtime.h>
#include <hip/hip_fp16.h>
#include <cstdint>
#include <cstddef>

typedef _Float16 f16x8 __attribute__((ext_vector_type(8)));
typedef _Float16 f16x4 __attribute__((ext_vector_type(4)));
typedef float    f32x4 __attribute__((ext_vector_type(4)));

// ---------------------------------------------------------------------------
// fake-quant with fractional bit-width interpolation (matches jax reference)
// ---------------------------------------------------------------------------
__device__ __forceinline__ float quant_interp(float v, float alpha) {
    float a    = fmaxf(alpha, 1.0f);
    float blo  = floorf(a);
    float frac = a - blo;
    float slo  = exp2f(blo) - 1.0f;
    float shi  = 2.0f * slo + 1.0f;
    float c    = fminf(fmaxf(v, -1.0f), 1.0f);
    float qlo  = rintf(c * slo) / slo;
    float qhi  = rintf(c * shi) / shi;
    return (1.0f - frac) * qlo + frac * qhi;
}

// ---------------------------------------------------------------------------
// column mean of alpha_a [OUT][IN] -> a_feat [IN], deterministic two-pass
// ---------------------------------------------------------------------------
__global__ void colsum_partial_kernel(const float* __restrict__ aA,
                                      float* __restrict__ partial,
                                      int IN, int rows_per) {
    int col = blockIdx.x * blockDim.x + threadIdx.x;
    size_t r0 = (size_t)blockIdx.y * rows_per;
    float s = 0.f;
    for (int r = 0; r < rows_per; ++r)
        s += aA[(r0 + r) * (size_t)IN + col];
    partial[(size_t)blockIdx.y * IN + col] = s;
}

__global__ void colsum_final_kernel(const float* __restrict__ partial,
                                    float* __restrict__ afeat,
                                    int IN, int nchunk, float inv) {
    int col = blockIdx.x * blockDim.x + threadIdx.x;
    float s = 0.f;
    for (int c = 0; c < nchunk; ++c)
        s += partial[(size_t)c * IN + col];
    afeat[col] = s * inv;
}

// ---------------------------------------------------------------------------
// quantize x [M][IN] with per-column alpha -> fp16
// ---------------------------------------------------------------------------
__global__ void quant_x_kernel(const float* __restrict__ x,
                               const float* __restrict__ afeat,
                               f16x4* __restrict__ qx, int IN, size_t n4) {
    size_t i = (size_t)blockIdx.x * blockDim.x + threadIdx.x;
    size_t stride = (size_t)gridDim.x * blockDim.x;
    for (; i < n4; i += stride) {
        size_t e = i * 4;
        int col = (int)(e % (size_t)IN);
        f32x4 xv = *(const f32x4*)(x + e);
        f32x4 av = *(const f32x4*)(afeat + col);
        f16x4 o;
        #pragma unroll
        for (int j = 0; j < 4; ++j) o[j] = (_Float16)quant_interp(xv[j], av[j]);
        qx[i] = o;
    }
}

__global__ void quant_w_kernel(const float* __restrict__ w,
                               const float* __restrict__ aw,
                               f16x4* __restrict__ qw, size_t n4) {
    size_t i = (size_t)blockIdx.x * blockDim.x + threadIdx.x;
    size_t stride = (size_t)gridDim.x * blockDim.x;
    for (; i < n4; i += stride) {
        f32x4 wv = *(const f32x4*)(w + i * 4);
        f32x4 av = *(const f32x4*)(aw + i * 4);
        f16x4 o;
        #pragma unroll
        for (int j = 0; j < 4; ++j) o[j] = (_Float16)quant_interp(wv[j], av[j]);
        qw[i] = o;
    }
}

// ---------------------------------------------------------------------------
// 256x256 8-phase NT GEMM, fp16 in / fp32 out, counted-vmcnt pipeline.
//   8 waves = 2(M) x 4(N); wave tile 128x64; acc[8][4] f32x4.
//   Wave m-frag mf -> abs row (mf>>2)*128 + wm*64 + (mf&3)*16   (rows die early)
//   Wave n-frag nf -> abs col (nf>>1)*128 + wn*32 + (nf&1)*16   (cols die early)
//   Phase (mh,nh): A-half mh + B-half nh; A-half0 dead after q1, B-half0 after
//   q2 -> during tile t stage: q0:A1(t+1) q1:B1(t+1) q2:A0(t+2) q3:B0(t+2);
//   one vmcnt(4) per tile boundary (tile t+1 fully landed, t+2's A0/B0 in
//   flight). XOR slot swizzle: phys slot = logical ^ (row&7), inverse applied
//   to the GLOBAL source (linear LDS dest; rule #21).
// ---------------------------------------------------------------------------
__device__ __forceinline__ void gload_lds16(const void* g, void* l) {
    __builtin_amdgcn_global_load_lds(
        (const __attribute__((address_space(1))) void*)g,
        (__attribute__((address_space(3))) void*)l, 16, 0, 0);
}

__device__ __forceinline__ f16x8 lds_frag(const _Float16* buf, int row, int ks, int hi) {
    const int sl = (ks * 4 + hi) ^ (row & 7);
    return *(const f16x8*)((const char*)buf + row * 128 + sl * 16);
}

#define PHASE(MH, NH, STAGE_STMT, BDRY_STMT)                                   \
    {                                                                          \
        f16x8 af[4][2], bf[2][2];                                              \
        _Pragma("unroll")                                                      \
        for (int mi = 0; mi < 4; ++mi) {                                       \
            const int row = (MH) * 128 + wm * 64 + mi * 16 + r15;              \
            af[mi][0] = lds_frag(Ab, row, 0, hi);                              \
            af[mi][1] = lds_frag(Ab, row, 1, hi);                              \
        }                                                                      \
        _Pragma("unroll")                                                      \
        for (int ni = 0; ni < 2; ++ni) {                                       \
            const int row = (NH) * 128 + wn * 32 + ni * 16 + r15;              \
            bf[ni][0] = lds_frag(Bb, row, 0, hi);                              \
            bf[ni][1] = lds_frag(Bb, row, 1, hi);                              \
        }                                                                      \
        STAGE_STMT;                                                            \
        __builtin_amdgcn_s_barrier();                                          \
        asm volatile("s_waitcnt lgkmcnt(0)" ::: "memory");                     \
        __builtin_amdgcn_sched_barrier(0);                                     \
        __builtin_amdgcn_s_setprio(1);                                         \
        _Pragma("unroll")                                                      \
        for (int mi = 0; mi < 4; ++mi)                                         \
            _Pragma("unroll")                                                  \
            for (int ni = 0; ni < 2; ++ni) {                                   \
                f32x4& ac = acc[(MH) * 4 + mi][(NH) * 2 + ni];                 \
                ac = __builtin_amdgcn_mfma_f32_16x16x32_f16(af[mi][0], bf[ni][0], ac, 0, 0, 0); \
                ac = __builtin_amdgcn_mfma_f32_16x16x32_f16(af[mi][1], bf[ni][1], ac, 0, 0, 0); \
            }                                                                  \
        __builtin_amdgcn_s_setprio(0);                                         \
        BDRY_STMT;                                                             \
        __builtin_amdgcn_s_barrier();                                          \
    }

__global__ __launch_bounds__(512, 2) void gemm8p_kernel(
    const _Float16* __restrict__ A,   // [M][K] qx
    const _Float16* __restrict__ B,   // [N][K] qw
    const float* __restrict__ bias,   // [N]
    float* __restrict__ C,            // [M][N]
    int M, int N, int K)
{
    constexpr int BK = 64;
    __shared__ _Float16 sA[2][256 * BK];   // 64 KiB
    __shared__ _Float16 sB[2][256 * BK];   // 64 KiB

    const int tid  = (int)threadIdx.x;
    const int lane = tid & 63;
    const int wave = tid >> 6;
    const int wm   = wave >> 2;    // 0..1
    const int wn   = wave & 3;     // 0..3
    const int r15  = lane & 15;
    const int hi   = lane >> 4;

    const int nbx = N >> 8;
    const int nwg = (M >> 8) * nbx;
    const int bid = (int)blockIdx.x;
    const int swz = (nwg & 7) ? bid : ((bid & 7) * (nwg >> 3) + (bid >> 3));
    const size_t bm0 = (size_t)(swz / nbx) << 8;
    const size_t bn0 = (size_t)(swz % nbx) << 8;

    const int nkt = K / BK;
    const _Float16* Agb = A + bm0 * K;
    const _Float16* Bgb = B + bn0 * K;

    // stage one half-tile (128 rows x 64 halfs): which 0=A0 1=A1 2=B0 3=B1
    auto STAGE = [&](int tile, int which) {
        if (tile >= nkt) return;
        const _Float16* g = (which < 2 ? Agb : Bgb) + (size_t)tile * BK;
        _Float16* lb = (which < 2 ? sA[tile & 1] : sB[tile & 1]);
        const int rb = (which & 1) << 7;
        #pragma unroll
        for (int rr = 0; rr < 2; ++rr) {
            const int row = rb + rr * 64 + (tid >> 3);
            const int sg  = (tid & 7) ^ (row & 7);
            gload_lds16(g + (size_t)row * K + sg * 8,
                        (char*)lb + ((rb + rr * 64) << 7) + (wave << 10));
        }
    };

    f32x4 acc[8][4] = {};

    // prologue: tile0 complete + tile1's A0,B0 in flight
    STAGE(0, 0); STAGE(0, 2); STAGE(0, 1); STAGE(0, 3);
    STAGE(1, 0); STAGE(1, 2);
    if (nkt > 1) { asm volatile("s_waitcnt vmcnt(4)" ::: "memory"); }
    else         { asm volatile("s_waitcnt vmcnt(0)" ::: "memory"); }
    __builtin_amdgcn_s_barrier();

    for (int t = 0; t < nkt; ++t) {
        const _Float16* Ab = sA[t & 1];
        const _Float16* Bb = sB[t & 1];

        PHASE(0, 0, STAGE(t + 1, 1), )
        PHASE(0, 1, STAGE(t + 1, 3), )
        PHASE(1, 0, STAGE(t + 2, 0), )
        PHASE(1, 1, STAGE(t + 2, 2),
              if (t + 2 < nkt) { asm volatile("s_waitcnt vmcnt(4)" ::: "memory"); }
              else             { asm volatile("s_waitcnt vmcnt(0)" ::: "memory"); })
    }

    // epilogue: C/D layout col = lane&15, row = (lane>>4)*4 + reg
    #pragma unroll
    for (int nf = 0; nf < 4; ++nf) {
        const size_t col = bn0 + (size_t)((nf >> 1) * 128 + wn * 32 + (nf & 1) * 16 + r15);
        const float bv = bias[col];
        #pragma unroll
        for (int mf = 0; mf < 8; ++mf) {
            const size_t row0 = bm0 + (size_t)((mf >> 2) * 128 + wm * 64 + (mf & 3) * 16 + hi * 4);
            #pragma unroll
            for (int r = 0; r < 4; ++r)
                C[(row0 + r) * N + col] = acc[mf][nf][r] + bv;
        }
    }
}

// ---------------------------------------------------------------------------
extern "C" void kernel_launch(void* const* d_in, const int* in_sizes, int n_in,
                              void* d_out, int out_size, void* d_ws, size_t ws_size,
                              hipStream_t stream) {
    const float* x    = (const float*)d_in[0];
    const float* w    = (const float*)d_in[1];
    const float* bias = (const float*)d_in[2];
    const float* aw   = (const float*)d_in[3];
    const float* aA   = (const float*)d_in[4];

    const int    OUT = in_sizes[2];
    const size_t wsz = (size_t)in_sizes[1];
    const int    IN  = (int)(wsz / OUT);
    const int    M   = in_sizes[0] / IN;    // 8192
    const int    N   = OUT;                 // 4096
    const int    K   = IN;                  // 4096

    char* ws = (char*)d_ws;
    _Float16* qx = (_Float16*)ws;                                   // M*K*2
    _Float16* qw = (_Float16*)(ws + (size_t)M * K * 2);             // N*K*2
    float* afeat   = (float*)(ws + (size_t)M * K * 2 + (size_t)N * K * 2);
    float* partial = afeat + K;                                     // 32*K

    const int NCHUNK = 32;
    dim3 g1(K / 256, NCHUNK);
    colsum_partial_kernel<<<g1, 256, 0, stream>>>(aA, partial, K, OUT / NCHUNK);
    colsum_final_kernel<<<K / 256, 256, 0, stream>>>(partial, afeat, K, NCHUNK,
                                                     1.0f / (float)OUT);

    quant_x_kernel<<<2048, 256, 0, stream>>>(x, afeat, (f16x4*)qx, K,
                                             (size_t)M * K / 4);
    quant_w_kernel<<<2048, 256, 0, stream>>>(w, aw, (f16x4*)qw,
                                             (size_t)N * K / 4);

    const int nwg = (M / 256) * (N / 256);
    gemm8p_kernel<<<nwg, 512, 0, stream>>>(qx, qw, bias, (float*)d_out,
                                           M, N, K);
}

// Round 3
// 396.801 us; speedup vs baseline: 1.1986x; 1.1468x over previous
//
#include <hip/hip_runtime.h>
#include <hip/hip_fp16.h>
#include <cstdint>
#include <cstddef>

typedef _Float16 f16x8 __attribute__((ext_vector_type(8)));
typedef _Float16 f16x4 __attribute__((ext_vector_type(4)));
typedef float    f32x4 __attribute__((ext_vector_type(4)));

// ---------------------------------------------------------------------------
// fake-quant with fractional bit-width interpolation (matches jax reference)
// divisions replaced by v_rcp_f32 (1 ulp; error ~1e-7 vs 0.031 absmax margin)
// ---------------------------------------------------------------------------
__device__ __forceinline__ float quant_interp(float v, float alpha) {
    float a    = fmaxf(alpha, 1.0f);
    float blo  = floorf(a);
    float frac = a - blo;
    float slo  = exp2f(blo) - 1.0f;
    float shi  = 2.0f * slo + 1.0f;
    float rslo = __builtin_amdgcn_rcpf(slo);
    float rshi = __builtin_amdgcn_rcpf(shi);
    float c    = fminf(fmaxf(v, -1.0f), 1.0f);
    float qlo  = rintf(c * slo) * rslo;
    float qhi  = rintf(c * shi) * rshi;
    return (1.0f - frac) * qlo + frac * qhi;
}

// ---------------------------------------------------------------------------
// column mean of alpha_a [OUT][IN] -> a_feat [IN], deterministic two-pass
// ---------------------------------------------------------------------------
__global__ void colsum_partial_kernel(const float* __restrict__ aA,
                                      float* __restrict__ partial,
                                      int IN, int rows_per) {
    int col = blockIdx.x * blockDim.x + threadIdx.x;
    size_t r0 = (size_t)blockIdx.y * rows_per;
    float s = 0.f;
    for (int r = 0; r < rows_per; ++r)
        s += aA[(r0 + r) * (size_t)IN + col];
    partial[(size_t)blockIdx.y * IN + col] = s;
}

__global__ void colsum_final_kernel(const float* __restrict__ partial,
                                    float* __restrict__ afeat,
                                    int IN, int nchunk, float inv) {
    int col = blockIdx.x * blockDim.x + threadIdx.x;
    float s = 0.f;
    for (int c = 0; c < nchunk; ++c)
        s += partial[(size_t)c * IN + col];
    afeat[col] = s * inv;
}

// ---------------------------------------------------------------------------
// quantize x [M][IN] with per-column alpha -> fp16
// ---------------------------------------------------------------------------
__global__ void quant_x_kernel(const float* __restrict__ x,
                               const float* __restrict__ afeat,
                               f16x4* __restrict__ qx, int IN, size_t n4) {
    size_t i = (size_t)blockIdx.x * blockDim.x + threadIdx.x;
    size_t stride = (size_t)gridDim.x * blockDim.x;
    for (; i < n4; i += stride) {
        size_t e = i * 4;
        int col = (int)(e % (size_t)IN);
        f32x4 xv = *(const f32x4*)(x + e);
        f32x4 av = *(const f32x4*)(afeat + col);
        f16x4 o;
        #pragma unroll
        for (int j = 0; j < 4; ++j) o[j] = (_Float16)quant_interp(xv[j], av[j]);
        qx[i] = o;
    }
}

__global__ void quant_w_kernel(const float* __restrict__ w,
                               const float* __restrict__ aw,
                               f16x4* __restrict__ qw, size_t n4) {
    size_t i = (size_t)blockIdx.x * blockDim.x + threadIdx.x;
    size_t stride = (size_t)gridDim.x * blockDim.x;
    for (; i < n4; i += stride) {
        f32x4 wv = *(const f32x4*)(w + i * 4);
        f32x4 av = *(const f32x4*)(aw + i * 4);
        f16x4 o;
        #pragma unroll
        for (int j = 0; j < 4; ++j) o[j] = (_Float16)quant_interp(wv[j], av[j]);
        qw[i] = o;
    }
}

// ---------------------------------------------------------------------------
// 256x256 NT GEMM, fp16 in / fp32 out, 2-phase/K-tile, minimal LDS traffic.
//   8 waves = 2(M) x 4(N); wave tile 128x64; acc[8][4] f32x4 (mf = mh*4+mi).
//   Phase 0 (mh=0): ds_read A-half0 (8xb128) + ALL B (8xb128, register-
//   resident across the tile); 32 MFMA. Phase 1 (mh=1): ds_read A-half1 (8);
//   32 MFMA.  24 ds_read_b128/wave/tile = the sharing minimum (196KB/CU/tile).
//   Counted-vmcnt staging (never 0 in loop):
//     ph0 stages B1(t+1),A1(t+1) -> buf^1 (regions dead since tile t-1)
//     ph1 stages A0(t+2),B0(t+2) -> buf[t&1] quadrants that died after ph0(t)
//     end-ph0: vmcnt(8) drains A1(t); end-ph1: vmcnt(6) drains A0,B0,B1(t+1)
//   XOR slot swizzle: phys slot = logical ^ (row&7); inverse applied to the
//   GLOBAL source, linear LDS dest (rule #21). 0 bank conflicts (measured).
// ---------------------------------------------------------------------------
__device__ __forceinline__ void gload_lds16(const void* g, void* l) {
    __builtin_amdgcn_global_load_lds(
        (const __attribute__((address_space(1))) void*)g,
        (__attribute__((address_space(3))) void*)l, 16, 0, 0);
}

__device__ __forceinline__ f16x8 lds_frag(const _Float16* buf, int row, int ks, int hi) {
    const int sl = (ks * 4 + hi) ^ (row & 7);
    return *(const f16x8*)((const char*)buf + row * 128 + sl * 16);
}

__global__ __launch_bounds__(512, 2) void gemm2p_kernel(
    const _Float16* __restrict__ A,   // [M][K] qx
    const _Float16* __restrict__ B,   // [N][K] qw
    const float* __restrict__ bias,   // [N]
    float* __restrict__ C,            // [M][N]
    int M, int N, int K)
{
    constexpr int BK = 64;
    __shared__ _Float16 sA[2][256 * BK];   // 64 KiB
    __shared__ _Float16 sB[2][256 * BK];   // 64 KiB

    const int tid  = (int)threadIdx.x;
    const int lane = tid & 63;
    const int wave = tid >> 6;
    const int wm   = wave >> 2;    // 0..1
    const int wn   = wave & 3;     // 0..3
    const int r15  = lane & 15;
    const int hi   = lane >> 4;

    const int nbx = N >> 8;
    const int nwg = (M >> 8) * nbx;
    const int bid = (int)blockIdx.x;
    const int swz = (nwg & 7) ? bid : ((bid & 7) * (nwg >> 3) + (bid >> 3));
    const size_t bm0 = (size_t)(swz / nbx) << 8;
    const size_t bn0 = (size_t)(swz % nbx) << 8;

    const int nkt = K / BK;
    const _Float16* Agb = A + bm0 * K;
    const _Float16* Bgb = B + bn0 * K;

    // stage one half-tile (128 rows x 64 halfs): which 0=A0 1=A1 2=B0 3=B1
    auto STAGE = [&](int tile, int which) {
        if (tile >= nkt) return;
        const _Float16* g = (which < 2 ? Agb : Bgb) + (size_t)tile * BK;
        _Float16* lb = (which < 2 ? sA[tile & 1] : sB[tile & 1]);
        const int rb = (which & 1) << 7;
        #pragma unroll
        for (int rr = 0; rr < 2; ++rr) {
            const int row = rb + rr * 64 + (tid >> 3);
            const int sg  = (tid & 7) ^ (row & 7);
            gload_lds16(g + (size_t)row * K + sg * 8,
                        (char*)lb + ((rb + rr * 64) << 7) + (wave << 10));
        }
    };

    f32x4 acc[8][4] = {};
    f16x8 bf[4][2];

    // prologue: issue order A0(0),B0(0),B1(0),A1(0),A0(1),B0(1) = 12 loads;
    // vmcnt(6) drains tile0's A0,B0,B1; leaves [A1(0),A0(1),B0(1)] in flight
    STAGE(0, 0); STAGE(0, 2); STAGE(0, 3); STAGE(0, 1);
    STAGE(1, 0); STAGE(1, 2);
    asm volatile("s_waitcnt vmcnt(6)" ::: "memory");
    __builtin_amdgcn_s_barrier();

    for (int t = 0; t < nkt; ++t) {
        const _Float16* Ab = sA[t & 1];
        const _Float16* Bb = sB[t & 1];
        f16x8 af[4][2];

        // -------- phase 0: mh=0; B register-resident for whole tile --------
        #pragma unroll
        for (int mi = 0; mi < 4; ++mi) {
            const int row = wm * 64 + mi * 16 + r15;
            af[mi][0] = lds_frag(Ab, row, 0, hi);
            af[mi][1] = lds_frag(Ab, row, 1, hi);
        }
        #pragma unroll
        for (int nf = 0; nf < 4; ++nf) {
            const int row = (nf >> 1) * 128 + wn * 32 + (nf & 1) * 16 + r15;
            bf[nf][0] = lds_frag(Bb, row, 0, hi);
            bf[nf][1] = lds_frag(Bb, row, 1, hi);
        }
        STAGE(t + 1, 3); STAGE(t + 1, 1);     // B1(t+1), A1(t+1)
        __builtin_amdgcn_s_barrier();
        asm volatile("s_waitcnt lgkmcnt(0)" ::: "memory");
        __builtin_amdgcn_sched_barrier(0);
        __builtin_amdgcn_s_setprio(1);
        #pragma unroll
        for (int mi = 0; mi < 4; ++mi)
            #pragma unroll
            for (int nf = 0; nf < 4; ++nf) {
                f32x4& ac = acc[mi][nf];
                ac = __builtin_amdgcn_mfma_f32_16x16x32_f16(af[mi][0], bf[nf][0], ac, 0, 0, 0);
                ac = __builtin_amdgcn_mfma_f32_16x16x32_f16(af[mi][1], bf[nf][1], ac, 0, 0, 0);
            }
        __builtin_amdgcn_s_setprio(0);
        asm volatile("s_waitcnt vmcnt(8)" ::: "memory");   // A1(t) landed
        __builtin_amdgcn_s_barrier();

        // -------- phase 1: mh=1 --------
        #pragma unroll
        for (int mi = 0; mi < 4; ++mi) {
            const int row = 128 + wm * 64 + mi * 16 + r15;
            af[mi][0] = lds_frag(Ab, row, 0, hi);
            af[mi][1] = lds_frag(Ab, row, 1, hi);
        }
        STAGE(t + 2, 0); STAGE(t + 2, 2);     // A0(t+2), B0(t+2)
        __builtin_amdgcn_s_barrier();
        asm volatile("s_waitcnt lgkmcnt(0)" ::: "memory");
        __builtin_amdgcn_sched_barrier(0);
        __builtin_amdgcn_s_setprio(1);
        #pragma unroll
        for (int mi = 0; mi < 4; ++mi)
            #pragma unroll
            for (int nf = 0; nf < 4; ++nf) {
                f32x4& ac = acc[4 + mi][nf];
                ac = __builtin_amdgcn_mfma_f32_16x16x32_f16(af[mi][0], bf[nf][0], ac, 0, 0, 0);
                ac = __builtin_amdgcn_mfma_f32_16x16x32_f16(af[mi][1], bf[nf][1], ac, 0, 0, 0);
            }
        __builtin_amdgcn_s_setprio(0);
        asm volatile("s_waitcnt vmcnt(6)" ::: "memory");   // tile t+1 complete
        __builtin_amdgcn_s_barrier();
    }

    // epilogue: C/D layout col = lane&15, row = (lane>>4)*4 + reg
    #pragma unroll
    for (int nf = 0; nf < 4; ++nf) {
        const size_t col = bn0 + (size_t)((nf >> 1) * 128 + wn * 32 + (nf & 1) * 16 + r15);
        const float bv = bias[col];
        #pragma unroll
        for (int mf = 0; mf < 8; ++mf) {
            const size_t row0 = bm0 + (size_t)((mf >> 2) * 128 + wm * 64 + (mf & 3) * 16 + hi * 4);
            #pragma unroll
            for (int r = 0; r < 4; ++r)
                C[(row0 + r) * N + col] = acc[mf][nf][r] + bv;
        }
    }
}

// ---------------------------------------------------------------------------
extern "C" void kernel_launch(void* const* d_in, const int* in_sizes, int n_in,
                              void* d_out, int out_size, void* d_ws, size_t ws_size,
                              hipStream_t stream) {
    const float* x    = (const float*)d_in[0];
    const float* w    = (const float*)d_in[1];
    const float* bias = (const float*)d_in[2];
    const float* aw   = (const float*)d_in[3];
    const float* aA   = (const float*)d_in[4];

    const int    OUT = in_sizes[2];
    const size_t wsz = (size_t)in_sizes[1];
    const int    IN  = (int)(wsz / OUT);
    const int    M   = in_sizes[0] / IN;    // 8192
    const int    N   = OUT;                 // 4096
    const int    K   = IN;                  // 4096

    char* ws = (char*)d_ws;
    _Float16* qx = (_Float16*)ws;                                   // M*K*2
    _Float16* qw = (_Float16*)(ws + (size_t)M * K * 2);             // N*K*2
    float* afeat   = (float*)(ws + (size_t)M * K * 2 + (size_t)N * K * 2);
    float* partial = afeat + K;                                     // 32*K

    const int NCHUNK = 32;
    dim3 g1(K / 256, NCHUNK);
    colsum_partial_kernel<<<g1, 256, 0, stream>>>(aA, partial, K, OUT / NCHUNK);
    colsum_final_kernel<<<K / 256, 256, 0, stream>>>(partial, afeat, K, NCHUNK,
                                                     1.0f / (float)OUT);

    quant_x_kernel<<<2048, 256, 0, stream>>>(x, afeat, (f16x4*)qx, K,
                                             (size_t)M * K / 4);
    quant_w_kernel<<<2048, 256, 0, stream>>>(w, aw, (f16x4*)qw,
                                             (size_t)N * K / 4);

    const int nwg = (M / 256) * (N / 256);
    gemm2p_kernel<<<nwg, 512, 0, stream>>>(qx, qw, bias, (float*)d_out,
                                           M, N, K);
}